// Round 1
// 389.434 us; speedup vs baseline: 1.2500x; 1.2500x over previous
//
#include <hip/hip_runtime.h>

// Problem constants
#define NPX   131072      // B*H*W = 32*64*64 pixels
#define CHN   128         // NUM_HIDDENS
#define HWN   4096        // H*W
#define EMB   64
#define NCODE 512

// ws layout (bytes)
#define WS_HIST 0         // 512 * u32
#define WS_LOSS 2048      // 1 * f32
#define WS_CC   4096      // 512 * f32
#define WS_PWT  8192      // 128*64 f32 (pre_w transposed, 32 KB)
#define WS_IDX  40960     // 131072 * i32 (512 KB)

// Scratch carved out of the decode-output region (out+1 .. out+16777216),
// which vq_decode fully overwrites at the end:
//   zbuf  = out + 8         : 8388608 f32 (z, [pixel][64]) -- 16B aligned
//   bestb = out + 8388616   : 524288 f32  (per-chunk best dist, [pixel][4])
//   bidxb = out + 8912904   : 524288 i32  (per-chunk best idx,  [pixel][4])
// ends at out+9437192 < out+16777217. decode reads none of these.

// --- prep: transpose pre_w to [c][d] for contiguous uniform s_loads;
//     cc[k] = sum_d cb[k][d]^2 replicating numpy pairwise-8 order, unfused.
__global__ __launch_bounds__(512) void vq_prep(const float* __restrict__ preW,
                                               const float* __restrict__ cb,
                                               float* __restrict__ preWT,
                                               float* __restrict__ cc) {
  int t = threadIdx.x;
  for (int i = t; i < CHN * EMB; i += 512) {
    int c = i >> 6, d = i & 63;
    preWT[i] = preW[d * CHN + c];   // preW is [64][128]
  }
  if (t < NCODE) {
    const float* row = cb + t * EMB;
    float r[8];
#pragma unroll
    for (int j = 0; j < 8; ++j) r[j] = __fmul_rn(row[j], row[j]);
#pragma unroll
    for (int b = 1; b < 8; ++b)
#pragma unroll
      for (int j = 0; j < 8; ++j)
        r[j] = __fadd_rn(r[j], __fmul_rn(row[b * 8 + j], row[b * 8 + j]));
    cc[t] = __fadd_rn(__fadd_rn(__fadd_rn(r[0], r[1]), __fadd_rn(r[2], r[3])),
                      __fadd_rn(__fadd_rn(r[4], r[5]), __fadd_rn(r[6], r[7])));
  }
}

// --- pre-conv: z[p][d] = sum_c A[b,c,hw]*preW[d,c] + preB[d]
// d split into two halves across blocks (grid 1024) for occupancy.
// Arithmetic per (p,d) chain identical to the fused version (sequential c,
// unfused mul+add).
__global__ __launch_bounds__(256) void vq_pre(const float* __restrict__ A,
                                              const float* __restrict__ preWT,
                                              const float* __restrict__ preB,
                                              float* __restrict__ zbuf) {
  int bid = blockIdx.x;
  int ph = bid & 511, dh = bid >> 9;     // dh in {0,1}
  int d0 = dh << 5;
  int p = ph * 256 + threadIdx.x;
  int b = p >> 12, hw = p & 4095;
  const float* Ab = A + (size_t)b * CHN * HWN + hw;

  float z[32];
#pragma unroll
  for (int d = 0; d < 32; ++d) z[d] = 0.f;
  for (int c = 0; c < CHN; c += 4) {
    float a0 = Ab[(size_t)(c + 0) * HWN];   // coalesced, 4-deep prefetch
    float a1 = Ab[(size_t)(c + 1) * HWN];
    float a2 = Ab[(size_t)(c + 2) * HWN];
    float a3 = Ab[(size_t)(c + 3) * HWN];
    const float* w = preWT + c * EMB + d0;  // wave-uniform -> s_load
#pragma unroll
    for (int d = 0; d < 32; ++d) z[d] = __fadd_rn(z[d], __fmul_rn(a0, w[d]));
    w += EMB;
#pragma unroll
    for (int d = 0; d < 32; ++d) z[d] = __fadd_rn(z[d], __fmul_rn(a1, w[d]));
    w += EMB;
#pragma unroll
    for (int d = 0; d < 32; ++d) z[d] = __fadd_rn(z[d], __fmul_rn(a2, w[d]));
    w += EMB;
#pragma unroll
    for (int d = 0; d < 32; ++d) z[d] = __fadd_rn(z[d], __fmul_rn(a3, w[d]));
  }
#pragma unroll
  for (int d = 0; d < 32; ++d) z[d] = __fadd_rn(z[d], preB[d0 + d]);

  float4* zp = (float4*)(zbuf + (size_t)p * 64 + d0);
#pragma unroll
  for (int i = 0; i < 8; ++i)
    zp[i] = make_float4(z[4 * i + 0], z[4 * i + 1], z[4 * i + 2], z[4 * i + 3]);
}

// --- search: split-K. Each block owns a 128-code chunk (uniform -> s_load),
// grid = 512 pixel-blocks * 4 chunks = 2048 blocks for occupancy.
__global__ __launch_bounds__(256) void vq_search(const float* __restrict__ zbuf,
                                                 const float* __restrict__ cb,
                                                 const float* __restrict__ cc,
                                                 float* __restrict__ bestb,
                                                 int* __restrict__ bidxb) {
  int bid = blockIdx.x;
  int q = bid & 3, ph = bid >> 2;
  int p = ph * 256 + threadIdx.x;

  float z[64];
  const float4* z4 = (const float4*)(zbuf + (size_t)p * 64);
#pragma unroll
  for (int i = 0; i < 16; ++i) {
    float4 v = z4[i];
    z[4 * i + 0] = v.x; z[4 * i + 1] = v.y; z[4 * i + 2] = v.z; z[4 * i + 3] = v.w;
  }

  // zz = sum z^2, numpy pairwise-8 order, unfused (same values as fused kernel)
  float r[8];
#pragma unroll
  for (int j = 0; j < 8; ++j) r[j] = __fmul_rn(z[j], z[j]);
#pragma unroll
  for (int bb = 1; bb < 8; ++bb)
#pragma unroll
    for (int j = 0; j < 8; ++j)
      r[j] = __fadd_rn(r[j], __fmul_rn(z[bb * 8 + j], z[bb * 8 + j]));
  float zz = __fadd_rn(__fadd_rn(__fadd_rn(r[0], r[1]), __fadd_rn(r[2], r[3])),
                       __fadd_rn(__fadd_rn(r[4], r[5]), __fadd_rn(r[6], r[7])));

  int k0 = q << 7;
  float best = 3.4e38f;
  int bidx = k0;
  for (int k = k0; k < k0 + 128; ++k) {
    const float* crow = cb + (k << 6);      // wave-uniform -> s_load
    float d0 = 0.f, d1 = 0.f, d2 = 0.f, d3 = 0.f;
#pragma unroll
    for (int dd = 0; dd < 64; dd += 4) {
      d0 = fmaf(crow[dd + 0], z[dd + 0], d0);
      d1 = fmaf(crow[dd + 1], z[dd + 1], d1);
      d2 = fmaf(crow[dd + 2], z[dd + 2], d2);
      d3 = fmaf(crow[dd + 3], z[dd + 3], d3);
    }
    float dot = (d0 + d1) + (d2 + d3);
    float dist = __fadd_rn(__fadd_rn(zz, cc[k]), -2.0f * dot);
    if (dist < best) { best = dist; bidx = k; }   // strict < : first-min tie-break
  }
  bestb[(size_t)p * 4 + q] = best;
  bidxb[(size_t)p * 4 + q] = bidx;
}

// --- combine: reduce 4 chunk minima in ascending-chunk order (identical
// tie-break to the monolithic loop), then loss partial + histogram + indices.
__global__ __launch_bounds__(256) void vq_combine(const float* __restrict__ zbuf,
                                                  const float* __restrict__ cb,
                                                  const float* __restrict__ bestb,
                                                  const int* __restrict__ bidxb,
                                                  float* __restrict__ outIdx,
                                                  int* __restrict__ wsIdx,
                                                  float* __restrict__ lossAcc,
                                                  unsigned int* __restrict__ hist) {
  int p = blockIdx.x * 256 + threadIdx.x;
  float4 bq = ((const float4*)bestb)[p];
  int4 iq = ((const int4*)bidxb)[p];
  float best = bq.x; int bidx = iq.x;
  if (bq.y < best) { best = bq.y; bidx = iq.y; }
  if (bq.z < best) { best = bq.z; bidx = iq.z; }
  if (bq.w < best) { best = bq.w; bidx = iq.w; }

  // loss partial: sum (q - z)^2 ; loss = 1.25 * mean
  const float4* q4 = (const float4*)(cb + (bidx << 6));
  const float4* z4 = (const float4*)(zbuf + (size_t)p * 64);
  float ls = 0.f;
#pragma unroll
  for (int i = 0; i < 16; ++i) {
    float4 qv = q4[i];
    float4 zv = z4[i];
    float e;
    e = __fsub_rn(qv.x, zv.x); ls = fmaf(e, e, ls);
    e = __fsub_rn(qv.y, zv.y); ls = fmaf(e, e, ls);
    e = __fsub_rn(qv.z, zv.z); ls = fmaf(e, e, ls);
    e = __fsub_rn(qv.w, zv.w); ls = fmaf(e, e, ls);
  }
#pragma unroll
  for (int off = 32; off; off >>= 1) ls += __shfl_xor(ls, off, 64);
  if ((threadIdx.x & 63) == 0) atomicAdd(lossAcc, ls);
  atomicAdd(&hist[bidx], 1u);
  wsIdx[p] = bidx;
  outIdx[p] = (float)bidx;
}

// --- decode: out[b,o,hw] = sum_d q[d] * postW[o,d] + postB[o]
// o split into 4 chunks of 32 across blocks (grid 2048) for occupancy;
// per-o arithmetic identical to the previous decode.
__global__ __launch_bounds__(256) void vq_decode(const float* __restrict__ cb,
                                                 const int* __restrict__ wsIdx,
                                                 const float* __restrict__ postW,
                                                 const float* __restrict__ postB,
                                                 float* __restrict__ dec) {
  int bid = blockIdx.x;
  int och = bid & 3, ph = bid >> 2;
  int o0 = och << 5;
  int p = ph * 256 + threadIdx.x;
  int b = p >> 12, hw = p & 4095;
  int k = wsIdx[p];
  float qv[64];
  const float4* q4 = (const float4*)(cb + (k << 6));
#pragma unroll
  for (int i = 0; i < 16; ++i) {
    float4 v = q4[i];
    qv[4 * i + 0] = v.x; qv[4 * i + 1] = v.y; qv[4 * i + 2] = v.z; qv[4 * i + 3] = v.w;
  }
  float* out = dec + (size_t)b * CHN * HWN + hw;
  for (int o = o0; o < o0 + 32; ++o) {
    const float* w = postW + o * EMB;       // wave-uniform -> s_load (8KB/chunk)
    float a0 = 0.f, a1 = 0.f, a2 = 0.f, a3 = 0.f;
#pragma unroll
    for (int dd = 0; dd < 64; dd += 4) {
      a0 = fmaf(qv[dd + 0], w[dd + 0], a0);
      a1 = fmaf(qv[dd + 1], w[dd + 1], a1);
      a2 = fmaf(qv[dd + 2], w[dd + 2], a2);
      a3 = fmaf(qv[dd + 3], w[dd + 3], a3);
    }
    out[(size_t)o * HWN] = ((a0 + a1) + (a2 + a3)) + postB[o];  // coalesced per o
  }
}

// --- finalize: loss scalar + perplexity
__global__ __launch_bounds__(512) void vq_final(const unsigned int* __restrict__ hist,
                                                const float* __restrict__ lossAcc,
                                                float* __restrict__ outLoss,
                                                float* __restrict__ outPerp) {
  __shared__ float sred[8];
  int t = threadIdx.x;
  float c = (float)hist[t];
  float pavg = c * (1.0f / 131072.0f);
  float term = pavg * logf(pavg + 1e-10f);
#pragma unroll
  for (int off = 32; off; off >>= 1) term += __shfl_xor(term, off, 64);
  if ((t & 63) == 0) sred[t >> 6] = term;
  __syncthreads();
  if (t == 0) {
    float s = 0.f;
    for (int i = 0; i < 8; ++i) s += sred[i];
    *outPerp = expf(-s);
    *outLoss = 1.25f * (*lossAcc) * (1.0f / 8388608.0f);
  }
}

extern "C" void kernel_launch(void* const* d_in, const int* in_sizes, int n_in,
                              void* d_out, int out_size, void* d_ws, size_t ws_size,
                              hipStream_t stream) {
  const float* A     = (const float*)d_in[0];
  const float* preW  = (const float*)d_in[1];
  const float* preB  = (const float*)d_in[2];
  const float* cb    = (const float*)d_in[3];
  const float* postW = (const float*)d_in[4];
  const float* postB = (const float*)d_in[5];
  float* out = (float*)d_out;

  char* ws = (char*)d_ws;
  unsigned int* hist = (unsigned int*)(ws + WS_HIST);
  float* lossAcc = (float*)(ws + WS_LOSS);
  float* cc      = (float*)(ws + WS_CC);
  float* preWT   = (float*)(ws + WS_PWT);
  int* wsIdx     = (int*)(ws + WS_IDX);

  // scratch inside the decode-output region (overwritten by vq_decode last)
  float* zbuf  = out + 8;                    // 16B-aligned
  float* bestb = out + 8388616;
  int*   bidxb = (int*)(out + 8912904);

  hipMemsetAsync(ws, 0, 2052, stream);  // zero hist + loss accumulator
  vq_prep<<<1, 512, 0, stream>>>(preW, cb, preWT, cc);
  vq_pre<<<1024, 256, 0, stream>>>(A, preWT, preB, zbuf);
  vq_search<<<2048, 256, 0, stream>>>(zbuf, cb, cc, bestb, bidxb);
  vq_combine<<<512, 256, 0, stream>>>(zbuf, cb, bestb, bidxb,
                                      out + 16777218, wsIdx, lossAcc, hist);
  vq_decode<<<2048, 256, 0, stream>>>(cb, wsIdx, postW, postB, out + 1);
  vq_final<<<1, 512, 0, stream>>>(hist, lossAcc, out, out + 16777217);
}